// Round 3
// baseline (1245.120 us; speedup 1.0000x reference)
//
#include <hip/hip_runtime.h>
#include <hip/hip_bf16.h>
#include <stdint.h>

// D-MPNN (chemprop MPNEncoder) forward. fp32 in/out; bf16 intermediates, MFMA GEMMs.
// Intermediates use a 320-col padded layout (cols 300..319 == 0).
// R6: gather commutes with GEMM: (amsg[b2a]-msg[b2revb])@W_h = Gh[b2a]-Hm[b2revb],
//   Hm = msg@W_h, Gh = gsum(Hm). Layer = streaming GEMM + gsum + combine.
// R7 changes vs R6 (GEMM latency-bound: MfmaUtil 13% == MFMA floor, HBM 19%,
// Occupancy 20% <- acc[4][5]=80 AGPR + 120 VGPR = ~200 unified -> 2 waves/SIMD):
//  - 8 waves/block (512 thr), tile 64x320, wave owns 32x80 -> acc[2][5]=40 AGPR,
//    ~100 unified regs -> 4-5 waves/SIMD. Inner loop structure unchanged (R4-proven).
//  - all GEMM A-paths contiguous bf16: f_bonds pre-converted to [2e5][160] (aliases
//    HmB, dead after M1); f_atoms pre-converted into concat buffer [1e5][480]
//    (aliases inpB, prepped after combine-2); readout gsum writes cols 0..319 of it.

#define H_DIM 300
#define HP 320
#define AF_DIM 133
#define BF_DIM 147
#define MAXNB 6

typedef __hip_bfloat16 bf16;
typedef __attribute__((ext_vector_type(8))) short short8;
typedef __attribute__((ext_vector_type(4))) float f32x4;
typedef __attribute__((ext_vector_type(2))) unsigned int uint2v;

__device__ __forceinline__ float b2f_raw(unsigned short u) {
    union { unsigned int i; float f; } v; v.i = ((unsigned int)u) << 16; return v.f;
}
__device__ __forceinline__ unsigned short f2b_raw(float f) {
    union { float f; unsigned int i; } v; v.f = f;
    unsigned int x = v.i;
    x += 0x7fffu + ((x >> 16) & 1u);   // RNE
    return (unsigned short)(x >> 16);
}

// ---------------------------------------------------------------------------
// Weight prep: Wt[n][k] (bf16, k-contiguous, n<320, k<nkt*32)
//   k < 320 : s1[k*300 + n]      (k < r1, n < 300)
//   k >= 320: s2[(k-320)*300 + n] (k-320 < r2, n < 300)
// ---------------------------------------------------------------------------
__global__ __launch_bounds__(256) void prep_wt(
    const float* __restrict__ s1, int r1,
    const float* __restrict__ s2, int r2,
    unsigned short* __restrict__ Wt, int nkt)
{
    const int Ktot = nkt * 32;
    const int idx = blockIdx.x * 256 + threadIdx.x;
    if (idx >= 320 * Ktot) return;
    const int n = idx % 320;
    const int k = idx / 320;
    float v = 0.f;
    if (n < H_DIM) {
        if (k < 320) { if (k < r1) v = s1[k * H_DIM + n]; }
        else { const int kk = k - 320; if (kk < r2) v = s2[kk * H_DIM + n]; }
    }
    Wt[n * Ktot + k] = f2b_raw(v);
}

// fp32 [M][W] -> bf16 [M][160-pad] rows at stride ostride (ushorts)
__global__ __launch_bounds__(256) void prep_cvt(
    const float* __restrict__ in, int W,
    unsigned short* __restrict__ outb, int ostride, int M)
{
    const int idx = blockIdx.x * 256 + threadIdx.x;
    if (idx >= M * 20) return;
    const int r = idx / 20;
    const int cc = idx - r * 20;
    uint4 o;
    unsigned short* op = (unsigned short*)&o;
#pragma unroll
    for (int j = 0; j < 8; ++j) {
        const int k = cc * 8 + j;
        op[j] = (k < W) ? f2b_raw(in[(long)r * W + k]) : 0;
    }
    *(uint4*)(outb + (long)r * ostride + cc * 8) = o;
}

// ---------------------------------------------------------------------------
// MFMA GEMM: out[M][320] (stride 640B) = act(A @ W (+bias)).
// 512 thr / 8 waves; tile 64x320; wave (wr=w&1, wc=w>>1) owns rows 32wr..+32,
// cols 80wc..+80 -> acc[2][5] (40 AGPR). BK=32, NKT iters. A bf16 contiguous,
// row stride ASTRIDE bytes. LDS A chunks XOR-swizzled (chunk c of row r at
// r*64 + (c^(r&3))*16), staged 8B/thread.
// ---------------------------------------------------------------------------
template <int NKT, int ASTRIDE, bool RELU_A, bool BIAS_RELU>
__global__ __launch_bounds__(512) void mfma_gemm(
    const unsigned short* __restrict__ Ab,
    const unsigned short* __restrict__ Wt,  // [320][NKT*32]
    const float* __restrict__ bias,
    bf16* __restrict__ out,
    int M)
{
    constexpr int KTOT = NKT * 32;

    __shared__ char As[2][64 * 64];   // 2 x 4KB double-buffered A
    __shared__ char Cs[16 * 640];     // 10KB epilogue staging

    const int t    = threadIdx.x;
    const int m0   = blockIdx.x * 64;
    const int wave = t >> 6;
    const int wr   = wave & 1;        // row half (0..1)
    const int wc   = wave >> 1;       // col quarter (0..3)
    const int lane = t & 63;
    const int l16  = lane & 15;
    const int quad = lane >> 4;
    const int swz  = ((quad ^ (l16 & 3)) << 4);

    // A-staging mapping: row am (0..63), 8B chunk c (0..7)
    const int am  = t >> 3;
    const int c   = t & 7;
    const int gm  = m0 + am;
    const bool mok = (gm < M);
    const int aoff = am * 64 + (((c >> 1) ^ (am & 3)) << 4) + (c & 1) * 8;

    auto load_a = [&](int kt) -> uint2v {
        uint2v v = {0u, 0u};
        if (mok) {
            v = *(const uint2v*)((const char*)Ab + (long)gm * ASTRIDE + kt * 64 + c * 8);
            if (RELU_A) {              // relu on bf16: clear negative lanes
                unsigned short* rp = (unsigned short*)&v;
#pragma unroll
                for (int j = 0; j < 4; ++j)
                    rp[j] = (rp[j] & 0x8000u) ? 0 : rp[j];
            }
        }
        return v;
    };

    auto load_b = [&](int kt, short8* bfr) {
        const int kbase = kt * 32 + quad * 8;
#pragma unroll
        for (int nt = 0; nt < 5; ++nt) {
            const int nn = wc * 80 + nt * 16 + l16;
            bfr[nt] = *(const short8*)(Wt + (long)nn * KTOT + kbase);
        }
    };

    f32x4 acc[2][5];
#pragma unroll
    for (int i = 0; i < 2; ++i)
#pragma unroll
        for (int j = 0; j < 5; ++j) acc[i][j] = (f32x4){0.f, 0.f, 0.f, 0.f};

    // prologue: stage A(0), fetch B(0)
    uint2v aval = load_a(0);
    *(uint2v*)(As[0] + aoff) = aval;
    short8 bfr[5];
    load_b(0, bfr);

    for (int kt = 0; kt < NKT; ++kt) {
        short8 bfr_n[5];
        if (kt + 1 < NKT) {                 // prefetch next iteration (global)
            aval = load_a(kt + 1);
            load_b(kt + 1, bfr_n);
        }
        __syncthreads();                    // As[kt&1] visible to all waves
        short8 afr[2];
#pragma unroll
        for (int mt = 0; mt < 2; ++mt)
            afr[mt] = *(const short8*)(As[kt & 1] + (wr * 32 + mt * 16 + l16) * 64 + swz);
#pragma unroll
        for (int nt = 0; nt < 5; ++nt)
#pragma unroll
            for (int mt = 0; mt < 2; ++mt)
                acc[mt][nt] = __builtin_amdgcn_mfma_f32_16x16x32_bf16(
                    afr[mt], bfr[nt], acc[mt][nt], 0, 0, 0);
        if (kt + 1 < NKT) {
            *(uint2v*)(As[(kt + 1) & 1] + aoff) = aval;  // safe: last read in kt-1
#pragma unroll
            for (int nt = 0; nt < 5; ++nt) bfr[nt] = bfr_n[nt];
        }
    }

    // epilogue: 4 strips of 16 rows; owning waves (wr == s>>1) write Cs, all copy
    for (int s = 0; s < 4; ++s) {
        __syncthreads();
        if (wr == (s >> 1)) {
            const int mt = s & 1;
#pragma unroll
            for (int nt = 0; nt < 5; ++nt) {
                const int col = wc * 80 + nt * 16 + l16;
                float bv = 0.f;
                if (BIAS_RELU) bv = (col < H_DIM) ? bias[col] : 0.f;
#pragma unroll
                for (int r = 0; r < 4; ++r) {
                    float v = acc[mt][nt][r] + bv;
                    if (BIAS_RELU) v = fmaxf(v, 0.f);
                    ((unsigned short*)Cs)[(quad * 4 + r) * HP + col] = f2b_raw(v);
                }
            }
        }
        __syncthreads();
        const int gr0 = m0 + s * 16;
#pragma unroll
        for (int i = 0; i < 2; ++i) {       // 640 16B-chunks, 512 threads
            const int idx = i * 512 + t;
            if (idx < 640) {
                const int row = idx / 40;   // 40 chunks per 640B row
                if (gr0 + row < M)
                    *(uint4*)((char*)out + (long)(gr0 + row) * 640 + (idx - row * 40) * 16)
                        = *(const uint4*)(Cs + idx * 16);
            }
        }
    }
}

// amsg[a][0:320] = sum_{j<6} msg[a2b[a][j]][0:320]; thread = (atom, 8-col chunk)
// out rows at stride ostride (ushorts)
__global__ __launch_bounds__(256) void gather_sum_kernel(
    const bf16* __restrict__ msg, const int* __restrict__ a2b,
    unsigned short* __restrict__ amsg, int ostride, int n_atoms)
{
    const int idx = blockIdx.x * 256 + threadIdx.x;
    if (idx >= n_atoms * (HP / 8)) return;
    const int a = idx / (HP / 8);
    const int cc = idx - a * (HP / 8);
    float s[8] = {0.f, 0.f, 0.f, 0.f, 0.f, 0.f, 0.f, 0.f};
    const int base = a * MAXNB;
#pragma unroll
    for (int j = 0; j < MAXNB; ++j) {
        const long b = a2b[base + j];
        const uint4 u = *(const uint4*)((const char*)msg + (b * HP + cc * 8) * 2);
        const unsigned short* up = (const unsigned short*)&u;
#pragma unroll
        for (int e = 0; e < 8; ++e) s[e] += b2f_raw(up[e]);
    }
    uint4 r;
    unsigned short* rp = (unsigned short*)&r;
#pragma unroll
    for (int e = 0; e < 8; ++e) rp[e] = f2b_raw(s[e]);
    *(uint4*)(amsg + (long)a * ostride + cc * 8) = r;
}

// msg'[b] = relu(inp[b] + Gh[b2a[b]] - Hm[b2revb[b]]); thread = (bond, 8-col chunk)
__global__ __launch_bounds__(256) void combine_kernel(
    const bf16* __restrict__ inp, const bf16* __restrict__ Gh,
    const bf16* __restrict__ Hm, const int* __restrict__ b2a,
    const int* __restrict__ b2revb, bf16* __restrict__ outm, int n_bonds)
{
    const int idx = blockIdx.x * 256 + threadIdx.x;
    if (idx >= n_bonds * (HP / 8)) return;
    const int b = idx / (HP / 8);
    const int cc = idx - b * (HP / 8);
    const long co = (long)cc * 16;
    const long ra = b2a[b];
    const long rb = b2revb[b];
    const uint4 vi = *(const uint4*)((const char*)inp + (long)b * 640 + co);
    const uint4 vg = *(const uint4*)((const char*)Gh + ra * 640 + co);
    const uint4 vh = *(const uint4*)((const char*)Hm + rb * 640 + co);
    const unsigned short* ip = (const unsigned short*)&vi;
    const unsigned short* gp = (const unsigned short*)&vg;
    const unsigned short* hp = (const unsigned short*)&vh;
    uint4 r;
    unsigned short* rp = (unsigned short*)&r;
#pragma unroll
    for (int e = 0; e < 8; ++e) {
        const float v = b2f_raw(ip[e]) + b2f_raw(gp[e]) - b2f_raw(hp[e]);
        rp[e] = f2b_raw(fmaxf(v, 0.f));
    }
    *(uint4*)((char*)outm + (long)b * 640 + co) = r;
}

// Per-molecule mean; atom_mol sorted ascending -> binary search range, no atomics.
__global__ __launch_bounds__(256) void seg_mean_kernel(
    const bf16* __restrict__ hidden, const int* __restrict__ atom_mol,
    float* __restrict__ out, int n_atoms)
{
    const int m = blockIdx.x;
    __shared__ int s_lo, s_hi;
    if (threadIdx.x == 0) {
        int lo = 0, hi = n_atoms;
        while (lo < hi) { int mid = (lo + hi) >> 1; if (atom_mol[mid] < m) lo = mid + 1; else hi = mid; }
        s_lo = lo;
        int lo2 = lo; hi = n_atoms;
        while (lo2 < hi) { int mid = (lo2 + hi) >> 1; if (atom_mol[mid] < m + 1) lo2 = mid + 1; else hi = mid; }
        s_hi = lo2;
    }
    __syncthreads();
    const int lo = s_lo, hi = s_hi;
    const float inv = 1.0f / (float)max(hi - lo, 1);
    for (int cpass = 0; cpass < 2; ++cpass) {
        const int c = cpass * 256 + threadIdx.x;
        if (c >= H_DIM) break;
        float s = 0.f;
        for (int a = lo; a < hi; ++a)
            s += b2f_raw(((const unsigned short*)hidden)[(long)a * HP + c]);
        out[(long)m * H_DIM + c] = s * inv;
    }
}

extern "C" void kernel_launch(void* const* d_in, const int* in_sizes, int n_in,
                              void* d_out, int out_size, void* d_ws, size_t ws_size,
                              hipStream_t stream)
{
    const float* f_atoms = (const float*)d_in[0];
    const float* f_bonds = (const float*)d_in[1];
    const float* W_i     = (const float*)d_in[2];
    const float* W_h     = (const float*)d_in[3];
    const float* W_o     = (const float*)d_in[4];
    const float* b_o     = (const float*)d_in[5];
    const int*  a2b      = (const int*)d_in[6];
    const int*  b2a      = (const int*)d_in[7];
    const int*  b2revb   = (const int*)d_in[8];
    const int*  atom_mol = (const int*)d_in[9];

    const int n_atoms = in_sizes[0] / AF_DIM;   // 100000
    const int n_bonds = in_sizes[1] / BF_DIM;   // 200000
    const int n_mols  = out_size / H_DIM;       // 4000

    char* ws = (char*)d_ws;
    size_t off = 0;
    auto alloc = [&](size_t bytes) {
        size_t o = off; off += (bytes + 255) & ~(size_t)255; return o;
    };
    bf16* inpB = (bf16*)(ws + alloc((size_t)n_bonds * HP * 2));   // 128 MB (raw inp)
    bf16* msgX = (bf16*)(ws + alloc((size_t)n_bonds * HP * 2));   // 128 MB (msg1/msg2)
    bf16* HmB  = (bf16*)(ws + alloc((size_t)n_bonds * HP * 2));   // 128 MB (Hm per layer)
    bf16* amsg = (bf16*)(ws + alloc((size_t)n_atoms * HP * 2));   //  64 MB (Gh)
    unsigned short* Wt1 = (unsigned short*)(ws + alloc(320 * 160 * 2));
    unsigned short* WtH = (unsigned short*)(ws + alloc(320 * 320 * 2));
    unsigned short* Wt3 = (unsigned short*)(ws + alloc(320 * 480 * 2));
    // Aliases (lifetime-disjoint):
    unsigned short* fb16    = (unsigned short*)HmB;   // f_bonds bf16 [2e5][160]; dead after M1
    unsigned short* atomcat = (unsigned short*)inpB;  // [1e5][480]: cols 0-319 gsum, 320+ f_atoms;
                                                      // prepped after combine-2 (inp dead)
    bf16* hidden = HmB;                               // HmB dead after combine-2

    const dim3 blk(256), blkg(512);

    // weight prep (Wt3: amsg part = W_o rows 133.., atom part = W_o rows 0..132)
    prep_wt<<<(320 * 160 + 255) / 256, blk, 0, stream>>>(W_i, BF_DIM, nullptr, 0, Wt1, 5);
    prep_wt<<<(320 * 320 + 255) / 256, blk, 0, stream>>>(W_h, H_DIM, nullptr, 0, WtH, 10);
    prep_wt<<<(320 * 480 + 255) / 256, blk, 0, stream>>>(W_o + (size_t)AF_DIM * H_DIM, H_DIM,
                                                         W_o, AF_DIM, Wt3, 15);

    const int gB = (n_bonds + 63) / 64;   // 3125
    const int gA = (n_atoms + 63) / 64;   // 1563
    const int gG = (n_atoms * (HP / 8) + 255) / 256;
    const int gC = (n_bonds * (HP / 8) + 255) / 256;

    // f_bonds -> bf16 [n_bonds][160] (into HmB area)
    prep_cvt<<<(n_bonds * 20 + 255) / 256, blk, 0, stream>>>(f_bonds, BF_DIM, fb16, 160, n_bonds);

    // inp = f_bonds16 @ W_i (raw; msg0 = relu(inp) folded into layer-1 A-load)
    mfma_gemm<5, 320, false, false><<<gB, blkg, 0, stream>>>(fb16, Wt1, nullptr, inpB, n_bonds);

    // layer 1: Hm = relu(inp)@W_h; Gh = gsum(Hm); msg1 = relu(inp + Gh[b2a] - Hm[b2revb])
    mfma_gemm<10, 640, true, false><<<gB, blkg, 0, stream>>>(
        (const unsigned short*)inpB, WtH, nullptr, HmB, n_bonds);
    gather_sum_kernel<<<gG, blk, 0, stream>>>(HmB, a2b, (unsigned short*)amsg, HP, n_atoms);
    combine_kernel<<<gC, blk, 0, stream>>>(inpB, amsg, HmB, b2a, b2revb, msgX, n_bonds);

    // layer 2
    mfma_gemm<10, 640, false, false><<<gB, blkg, 0, stream>>>(
        (const unsigned short*)msgX, WtH, nullptr, HmB, n_bonds);
    gather_sum_kernel<<<gG, blk, 0, stream>>>(HmB, a2b, (unsigned short*)amsg, HP, n_atoms);
    combine_kernel<<<gC, blk, 0, stream>>>(inpB, amsg, HmB, b2a, b2revb, msgX, n_bonds);

    // readout: atomcat cols 320+ = f_atoms bf16 (inp dead now); cols 0-319 = gsum(msg2)
    prep_cvt<<<(n_atoms * 20 + 255) / 256, blk, 0, stream>>>(f_atoms, AF_DIM, atomcat + 320, 480, n_atoms);
    gather_sum_kernel<<<gG, blk, 0, stream>>>(msgX, a2b, atomcat, 480, n_atoms);
    mfma_gemm<15, 960, false, true><<<gA, blkg, 0, stream>>>(atomcat, Wt3, b_o, hidden, n_atoms);

    // per-molecule mean
    seg_mean_kernel<<<n_mols, blk, 0, stream>>>(hidden, atom_mol, (float*)d_out, n_atoms);
}

// Round 4
// 1100.684 us; speedup vs baseline: 1.1312x; 1.1312x over previous
//
#include <hip/hip_runtime.h>
#include <hip/hip_bf16.h>
#include <stdint.h>

// D-MPNN (chemprop MPNEncoder) forward. fp32 in/out; bf16 intermediates, MFMA GEMMs.
// Intermediates use a 320-col padded layout (cols 300..319 == 0).
// R6: gather commutes with GEMM: (amsg[b2a]-msg[b2revb])@W_h = Gh[b2a]-Hm[b2revb],
//   Hm = msg@W_h, Gh = gsum(Hm). Layer = streaming GEMM + gsum + combine.
// R8: barrier-free GEMM. R4-R7 all latency-serialized by the per-K-step
// __syncthreads (vmcnt(0) drain -> prefetch depth capped at 1, ~2400cyc exposed
// per K-step; R6 time == rounds x NKT x latency exactly). Fix: drop LDS-A staging;
// each wave loads its own A-fragments global->VGPR (4x redundancy absorbed by L1:
// same 64 lines, reused across kt pairs). Zero barriers / zero LDS in K-loop;
// compiler pipelines freely. Epilogue LDS transpose unchanged (10KB).

#define H_DIM 300
#define HP 320
#define AF_DIM 133
#define BF_DIM 147
#define MAXNB 6

typedef __hip_bfloat16 bf16;
typedef __attribute__((ext_vector_type(8))) short short8;
typedef __attribute__((ext_vector_type(4))) float f32x4;

__device__ __forceinline__ float b2f_raw(unsigned short u) {
    union { unsigned int i; float f; } v; v.i = ((unsigned int)u) << 16; return v.f;
}
__device__ __forceinline__ unsigned short f2b_raw(float f) {
    union { float f; unsigned int i; } v; v.f = f;
    unsigned int x = v.i;
    x += 0x7fffu + ((x >> 16) & 1u);   // RNE
    return (unsigned short)(x >> 16);
}

// ---------------------------------------------------------------------------
// Weight prep: Wt[n][k] (bf16, k-contiguous, n<320, k<nkt*32)
//   k < 320 : s1[k*300 + n]      (k < r1, n < 300)
//   k >= 320: s2[(k-320)*300 + n] (k-320 < r2, n < 300)
// ---------------------------------------------------------------------------
__global__ __launch_bounds__(256) void prep_wt(
    const float* __restrict__ s1, int r1,
    const float* __restrict__ s2, int r2,
    unsigned short* __restrict__ Wt, int nkt)
{
    const int Ktot = nkt * 32;
    const int idx = blockIdx.x * 256 + threadIdx.x;
    if (idx >= 320 * Ktot) return;
    const int n = idx % 320;
    const int k = idx / 320;
    float v = 0.f;
    if (n < H_DIM) {
        if (k < 320) { if (k < r1) v = s1[k * H_DIM + n]; }
        else { const int kk = k - 320; if (kk < r2) v = s2[kk * H_DIM + n]; }
    }
    Wt[n * Ktot + k] = f2b_raw(v);
}

// fp32 [M][W] -> bf16 [M][160-pad] rows at stride ostride (ushorts)
__global__ __launch_bounds__(256) void prep_cvt(
    const float* __restrict__ in, int W,
    unsigned short* __restrict__ outb, int ostride, int M)
{
    const int idx = blockIdx.x * 256 + threadIdx.x;
    if (idx >= M * 20) return;
    const int r = idx / 20;
    const int cc = idx - r * 20;
    uint4 o;
    unsigned short* op = (unsigned short*)&o;
#pragma unroll
    for (int j = 0; j < 8; ++j) {
        const int k = cc * 8 + j;
        op[j] = (k < W) ? f2b_raw(in[(long)r * W + k]) : 0;
    }
    *(uint4*)(outb + (long)r * ostride + cc * 8) = o;
}

// ---------------------------------------------------------------------------
// MFMA GEMM, barrier-free: out[M][320] (stride 640B) = act(A @ W (+bias)).
// 256 thr / 4 waves; tile 64x320; wave wc owns cols 80wc..+80, all 64 rows:
// acc[4][5] (80 AGPR). BK=32, NKT iters. A bf16 contiguous, row stride ASTR
// (elements). Per K-step each wave loads its own A-fragments directly
// global->VGPR: afr[mt] = A[16mt+l16][kt*32+quad*8 ..+8]. No LDS, no barriers
// in the K-loop. OOB rows clamped (garbage rows; C-store guards).
// ---------------------------------------------------------------------------
template <int NKT, int ASTR, bool RELU_A, bool BIAS_RELU>
__global__ __launch_bounds__(256) void mfma_gemm(
    const unsigned short* __restrict__ Ab,
    const unsigned short* __restrict__ Wt,  // [320][NKT*32]
    const float* __restrict__ bias,
    bf16* __restrict__ out,
    int M)
{
    constexpr int KTOT = NKT * 32;

    __shared__ char Cs[16 * 640];     // 10KB epilogue staging only

    const int t    = threadIdx.x;
    const int m0   = blockIdx.x * 64;
    const int wc   = t >> 6;          // wave = col strip
    const int lane = t & 63;
    const int l16  = lane & 15;
    const int quad = lane >> 4;

    // Per-lane A base offsets (elements), rows clamped to M-1
    long arow[4];
#pragma unroll
    for (int mt = 0; mt < 4; ++mt)
        arow[mt] = (long)min(m0 + mt * 16 + l16, M - 1) * ASTR + quad * 8;

    auto load_a = [&](int kt, short8* afr) {
#pragma unroll
        for (int mt = 0; mt < 4; ++mt) {
            short8 v = *(const short8*)(Ab + arow[mt] + kt * 32);
            if (RELU_A) {              // relu on bf16: clear negative lanes
                unsigned short* rp = (unsigned short*)&v;
#pragma unroll
                for (int j = 0; j < 8; ++j)
                    rp[j] = (rp[j] & 0x8000u) ? 0 : rp[j];
            }
            afr[mt] = v;
        }
    };

    auto load_b = [&](int kt, short8* bfr) {
        const int kbase = kt * 32 + quad * 8;
#pragma unroll
        for (int nt = 0; nt < 5; ++nt) {
            const int nn = wc * 80 + nt * 16 + l16;
            bfr[nt] = *(const short8*)(Wt + (long)nn * KTOT + kbase);
        }
    };

    f32x4 acc[4][5];
#pragma unroll
    for (int i = 0; i < 4; ++i)
#pragma unroll
        for (int j = 0; j < 5; ++j) acc[i][j] = (f32x4){0.f, 0.f, 0.f, 0.f};

    // depth-1 explicit prefetch; no barriers -> compiler may deepen freely
    short8 afr[4], bfr[5], afr_n[4], bfr_n[5];
    load_a(0, afr);
    load_b(0, bfr);

    for (int kt = 0; kt < NKT; ++kt) {
        if (kt + 1 < NKT) {
            load_a(kt + 1, afr_n);
            load_b(kt + 1, bfr_n);
        }
#pragma unroll
        for (int nt = 0; nt < 5; ++nt)
#pragma unroll
            for (int mt = 0; mt < 4; ++mt)
                acc[mt][nt] = __builtin_amdgcn_mfma_f32_16x16x32_bf16(
                    afr[mt], bfr[nt], acc[mt][nt], 0, 0, 0);
        if (kt + 1 < NKT) {
#pragma unroll
            for (int mt = 0; mt < 4; ++mt) afr[mt] = afr_n[mt];
#pragma unroll
            for (int nt = 0; nt < 5; ++nt) bfr[nt] = bfr_n[nt];
        }
    }

    // epilogue: per 16-row strip, LDS transpose -> coalesced 16B stores
    for (int mt = 0; mt < 4; ++mt) {
        __syncthreads();
#pragma unroll
        for (int nt = 0; nt < 5; ++nt) {
            const int col = wc * 80 + nt * 16 + l16;
            float bv = 0.f;
            if (BIAS_RELU) bv = (col < H_DIM) ? bias[col] : 0.f;
#pragma unroll
            for (int r = 0; r < 4; ++r) {
                float v = acc[mt][nt][r] + bv;
                if (BIAS_RELU) v = fmaxf(v, 0.f);
                ((unsigned short*)Cs)[(quad * 4 + r) * HP + col] = f2b_raw(v);
            }
        }
        __syncthreads();
        const int gr0 = m0 + mt * 16;
#pragma unroll
        for (int i = 0; i < 3; ++i) {       // 640 16B-chunks, 256 threads
            const int idx = i * 256 + t;
            if (idx < 640) {
                const int row = idx / 40;   // 40 chunks per 640B row
                if (gr0 + row < M)
                    *(uint4*)((char*)out + (long)(gr0 + row) * 640 + (idx - row * 40) * 16)
                        = *(const uint4*)(Cs + idx * 16);
            }
        }
    }
}

// amsg[a][0:320] = sum_{j<6} msg[a2b[a][j]][0:320]; thread = (atom, 8-col chunk)
// out rows at stride ostride (ushorts)
__global__ __launch_bounds__(256) void gather_sum_kernel(
    const bf16* __restrict__ msg, const int* __restrict__ a2b,
    unsigned short* __restrict__ amsg, int ostride, int n_atoms)
{
    const int idx = blockIdx.x * 256 + threadIdx.x;
    if (idx >= n_atoms * (HP / 8)) return;
    const int a = idx / (HP / 8);
    const int cc = idx - a * (HP / 8);
    float s[8] = {0.f, 0.f, 0.f, 0.f, 0.f, 0.f, 0.f, 0.f};
    const int base = a * MAXNB;
#pragma unroll
    for (int j = 0; j < MAXNB; ++j) {
        const long b = a2b[base + j];
        const uint4 u = *(const uint4*)((const char*)msg + (b * HP + cc * 8) * 2);
        const unsigned short* up = (const unsigned short*)&u;
#pragma unroll
        for (int e = 0; e < 8; ++e) s[e] += b2f_raw(up[e]);
    }
    uint4 r;
    unsigned short* rp = (unsigned short*)&r;
#pragma unroll
    for (int e = 0; e < 8; ++e) rp[e] = f2b_raw(s[e]);
    *(uint4*)(amsg + (long)a * ostride + cc * 8) = r;
}

// msg'[b] = relu(inp[b] + Gh[b2a[b]] - Hm[b2revb[b]]); thread = (bond, 8-col chunk)
__global__ __launch_bounds__(256) void combine_kernel(
    const bf16* __restrict__ inp, const bf16* __restrict__ Gh,
    const bf16* __restrict__ Hm, const int* __restrict__ b2a,
    const int* __restrict__ b2revb, bf16* __restrict__ outm, int n_bonds)
{
    const int idx = blockIdx.x * 256 + threadIdx.x;
    if (idx >= n_bonds * (HP / 8)) return;
    const int b = idx / (HP / 8);
    const int cc = idx - b * (HP / 8);
    const long co = (long)cc * 16;
    const long ra = b2a[b];
    const long rb = b2revb[b];
    const uint4 vi = *(const uint4*)((const char*)inp + (long)b * 640 + co);
    const uint4 vg = *(const uint4*)((const char*)Gh + ra * 640 + co);
    const uint4 vh = *(const uint4*)((const char*)Hm + rb * 640 + co);
    const unsigned short* ip = (const unsigned short*)&vi;
    const unsigned short* gp = (const unsigned short*)&vg;
    const unsigned short* hp = (const unsigned short*)&vh;
    uint4 r;
    unsigned short* rp = (unsigned short*)&r;
#pragma unroll
    for (int e = 0; e < 8; ++e) {
        const float v = b2f_raw(ip[e]) + b2f_raw(gp[e]) - b2f_raw(hp[e]);
        rp[e] = f2b_raw(fmaxf(v, 0.f));
    }
    *(uint4*)((char*)outm + (long)b * 640 + co) = r;
}

// Per-molecule mean; atom_mol sorted ascending -> binary search range, no atomics.
__global__ __launch_bounds__(256) void seg_mean_kernel(
    const bf16* __restrict__ hidden, const int* __restrict__ atom_mol,
    float* __restrict__ out, int n_atoms)
{
    const int m = blockIdx.x;
    __shared__ int s_lo, s_hi;
    if (threadIdx.x == 0) {
        int lo = 0, hi = n_atoms;
        while (lo < hi) { int mid = (lo + hi) >> 1; if (atom_mol[mid] < m) lo = mid + 1; else hi = mid; }
        s_lo = lo;
        int lo2 = lo; hi = n_atoms;
        while (lo2 < hi) { int mid = (lo2 + hi) >> 1; if (atom_mol[mid] < m + 1) lo2 = mid + 1; else hi = mid; }
        s_hi = lo2;
    }
    __syncthreads();
    const int lo = s_lo, hi = s_hi;
    const float inv = 1.0f / (float)max(hi - lo, 1);
    for (int cpass = 0; cpass < 2; ++cpass) {
        const int c = cpass * 256 + threadIdx.x;
        if (c >= H_DIM) break;
        float s = 0.f;
        for (int a = lo; a < hi; ++a)
            s += b2f_raw(((const unsigned short*)hidden)[(long)a * HP + c]);
        out[(long)m * H_DIM + c] = s * inv;
    }
}

extern "C" void kernel_launch(void* const* d_in, const int* in_sizes, int n_in,
                              void* d_out, int out_size, void* d_ws, size_t ws_size,
                              hipStream_t stream)
{
    const float* f_atoms = (const float*)d_in[0];
    const float* f_bonds = (const float*)d_in[1];
    const float* W_i     = (const float*)d_in[2];
    const float* W_h     = (const float*)d_in[3];
    const float* W_o     = (const float*)d_in[4];
    const float* b_o     = (const float*)d_in[5];
    const int*  a2b      = (const int*)d_in[6];
    const int*  b2a      = (const int*)d_in[7];
    const int*  b2revb   = (const int*)d_in[8];
    const int*  atom_mol = (const int*)d_in[9];

    const int n_atoms = in_sizes[0] / AF_DIM;   // 100000
    const int n_bonds = in_sizes[1] / BF_DIM;   // 200000
    const int n_mols  = out_size / H_DIM;       // 4000

    char* ws = (char*)d_ws;
    size_t off = 0;
    auto alloc = [&](size_t bytes) {
        size_t o = off; off += (bytes + 255) & ~(size_t)255; return o;
    };
    bf16* inpB = (bf16*)(ws + alloc((size_t)n_bonds * HP * 2));   // 128 MB (raw inp)
    bf16* msgX = (bf16*)(ws + alloc((size_t)n_bonds * HP * 2));   // 128 MB (msg1/msg2)
    bf16* HmB  = (bf16*)(ws + alloc((size_t)n_bonds * HP * 2));   // 128 MB (Hm per layer)
    bf16* amsg = (bf16*)(ws + alloc((size_t)n_atoms * HP * 2));   //  64 MB (Gh)
    unsigned short* Wt1 = (unsigned short*)(ws + alloc(320 * 160 * 2));
    unsigned short* WtH = (unsigned short*)(ws + alloc(320 * 320 * 2));
    unsigned short* Wt3 = (unsigned short*)(ws + alloc(320 * 480 * 2));
    // Aliases (lifetime-disjoint):
    unsigned short* fb16    = (unsigned short*)HmB;   // f_bonds bf16 [2e5][160]; dead after M1
    unsigned short* atomcat = (unsigned short*)inpB;  // [1e5][480]: cols 0-319 gsum, 320+ f_atoms;
                                                      // prepped after combine-2 (inp dead)
    bf16* hidden = HmB;                               // HmB dead after combine-2

    const dim3 blk(256);

    // weight prep (Wt3: amsg part = W_o rows 133.., atom part = W_o rows 0..132)
    prep_wt<<<(320 * 160 + 255) / 256, blk, 0, stream>>>(W_i, BF_DIM, nullptr, 0, Wt1, 5);
    prep_wt<<<(320 * 320 + 255) / 256, blk, 0, stream>>>(W_h, H_DIM, nullptr, 0, WtH, 10);
    prep_wt<<<(320 * 480 + 255) / 256, blk, 0, stream>>>(W_o + (size_t)AF_DIM * H_DIM, H_DIM,
                                                         W_o, AF_DIM, Wt3, 15);

    const int gB = (n_bonds + 63) / 64;   // 3125
    const int gA = (n_atoms + 63) / 64;   // 1563
    const int gG = (n_atoms * (HP / 8) + 255) / 256;
    const int gC = (n_bonds * (HP / 8) + 255) / 256;

    // f_bonds -> bf16 [n_bonds][160] (into HmB area)
    prep_cvt<<<(n_bonds * 20 + 255) / 256, blk, 0, stream>>>(f_bonds, BF_DIM, fb16, 160, n_bonds);

    // inp = f_bonds16 @ W_i (raw; msg0 = relu(inp) folded into layer-1 A-load)
    mfma_gemm<5, 160, false, false><<<gB, blk, 0, stream>>>(fb16, Wt1, nullptr, inpB, n_bonds);

    // layer 1: Hm = relu(inp)@W_h; Gh = gsum(Hm); msg1 = relu(inp + Gh[b2a] - Hm[b2revb])
    mfma_gemm<10, 320, true, false><<<gB, blk, 0, stream>>>(
        (const unsigned short*)inpB, WtH, nullptr, HmB, n_bonds);
    gather_sum_kernel<<<gG, blk, 0, stream>>>(HmB, a2b, (unsigned short*)amsg, HP, n_atoms);
    combine_kernel<<<gC, blk, 0, stream>>>(inpB, amsg, HmB, b2a, b2revb, msgX, n_bonds);

    // layer 2
    mfma_gemm<10, 320, false, false><<<gB, blk, 0, stream>>>(
        (const unsigned short*)msgX, WtH, nullptr, HmB, n_bonds);
    gather_sum_kernel<<<gG, blk, 0, stream>>>(HmB, a2b, (unsigned short*)amsg, HP, n_atoms);
    combine_kernel<<<gC, blk, 0, stream>>>(inpB, amsg, HmB, b2a, b2revb, msgX, n_bonds);

    // readout: atomcat cols 320+ = f_atoms bf16 (inp dead now); cols 0-319 = gsum(msg2)
    prep_cvt<<<(n_atoms * 20 + 255) / 256, blk, 0, stream>>>(f_atoms, AF_DIM, atomcat + 320, 480, n_atoms);
    gather_sum_kernel<<<gG, blk, 0, stream>>>(msgX, a2b, atomcat, 480, n_atoms);
    mfma_gemm<15, 480, false, true><<<gA, blk, 0, stream>>>(atomcat, Wt3, b_o, hidden, n_atoms);

    // per-molecule mean
    seg_mean_kernel<<<n_mols, blk, 0, stream>>>(hidden, atom_mol, (float*)d_out, n_atoms);
}

// Round 6
// 1039.886 us; speedup vs baseline: 1.1974x; 1.0585x over previous
//
#include <hip/hip_runtime.h>
#include <hip/hip_bf16.h>
#include <stdint.h>

// D-MPNN (chemprop MPNEncoder) forward. fp32 in/out; bf16 intermediates, MFMA GEMMs.
// Intermediates use a 320-col padded layout (cols 300..319 == 0).
// R6: gather commutes with GEMM: (amsg[b2a]-msg[b2revb])@W_h = Gh[b2a]-Hm[b2revb],
//   Hm = msg@W_h, Gh = gsum(Hm). Layer = streaming GEMM + gsum + combine.
// R9/R10: A-staging via __builtin_amdgcn_global_load_lds (width 16). R4/R6/R8 all
// pinned at 10-14% MfmaUtil by VGPR-round-trip staging + full vmcnt drain per
// K-step. gload_lds removes the round trip (async global->LDS, drained once by
// the pre-barrier vmcnt, under the MFMA block) - the measured 1.35-1.7x lever
// (m151/m193) at this exact loop structure. LDS linear (gload_lds forbids
// swizzle); relu applied on the ds_read side; B prefetch dropped (L2-resident)
// to cut 40 VGPR. R10 = R9 resubmit after infra failure (no counters), with
// the runtime-indexed LDS-pointer array replaced by named pointers (rule #20).

#define H_DIM 300
#define HP 320
#define AF_DIM 133
#define BF_DIM 147
#define MAXNB 6

typedef __hip_bfloat16 bf16;
typedef __attribute__((ext_vector_type(8))) short short8;
typedef __attribute__((ext_vector_type(4))) float f32x4;

__device__ __forceinline__ float b2f_raw(unsigned short u) {
    union { unsigned int i; float f; } v; v.i = ((unsigned int)u) << 16; return v.f;
}
__device__ __forceinline__ unsigned short f2b_raw(float f) {
    union { float f; unsigned int i; } v; v.f = f;
    unsigned int x = v.i;
    x += 0x7fffu + ((x >> 16) & 1u);   // RNE
    return (unsigned short)(x >> 16);
}

// async 16B global -> LDS (no VGPR round trip)
__device__ __forceinline__ void gload16(const void* g, void* l) {
    __builtin_amdgcn_global_load_lds(
        (const __attribute__((address_space(1))) unsigned int*)g,
        (__attribute__((address_space(3))) unsigned int*)l,
        16, 0, 0);
}

// ---------------------------------------------------------------------------
// Weight prep: Wt[n][k] (bf16, k-contiguous, n<320, k<nkt*32)
//   k < 320 : s1[k*300 + n]      (k < r1, n < 300)
//   k >= 320: s2[(k-320)*300 + n] (k-320 < r2, n < 300)
// ---------------------------------------------------------------------------
__global__ __launch_bounds__(256) void prep_wt(
    const float* __restrict__ s1, int r1,
    const float* __restrict__ s2, int r2,
    unsigned short* __restrict__ Wt, int nkt)
{
    const int Ktot = nkt * 32;
    const int idx = blockIdx.x * 256 + threadIdx.x;
    if (idx >= 320 * Ktot) return;
    const int n = idx % 320;
    const int k = idx / 320;
    float v = 0.f;
    if (n < H_DIM) {
        if (k < 320) { if (k < r1) v = s1[k * H_DIM + n]; }
        else { const int kk = k - 320; if (kk < r2) v = s2[kk * H_DIM + n]; }
    }
    Wt[n * Ktot + k] = f2b_raw(v);
}

// fp32 [M][W] -> bf16 [M][160-pad] rows at stride ostride (ushorts)
__global__ __launch_bounds__(256) void prep_cvt(
    const float* __restrict__ in, int W,
    unsigned short* __restrict__ outb, int ostride, int M)
{
    const int idx = blockIdx.x * 256 + threadIdx.x;
    if (idx >= M * 20) return;
    const int r = idx / 20;
    const int cc = idx - r * 20;
    uint4 o;
    unsigned short* op = (unsigned short*)&o;
#pragma unroll
    for (int j = 0; j < 8; ++j) {
        const int k = cc * 8 + j;
        op[j] = (k < W) ? f2b_raw(in[(long)r * W + k]) : 0;
    }
    *(uint4*)(outb + (long)r * ostride + cc * 8) = o;
}

// ---------------------------------------------------------------------------
// MFMA GEMM: out[M][320] (stride 640B) = act(A @ W (+bias)).
// 256 thr / 4 waves; tile 64x320; wave wc owns cols 80wc..+80, all 64 rows:
// acc[4][5] (80 AGPR). BK=32, NKT iters. A bf16 contiguous, row stride ASTR
// (elements). A staged by global_load_lds: thread t -> 16B (row t>>2, chunk
// t&3), LDS linear [64][64B], double-buffered. Wave-uniform-dest rule holds:
// lane l of wave w stages to As + w*1024 + l*16 (base = readfirstlane ptr,
// +lane*16 by HW). B loaded global->VGPR per step (Wt is L2-resident). One
// __syncthreads per K-step (drains the async stage issued one full MFMA block
// earlier). OOB rows clamped; C-store guards.
// ---------------------------------------------------------------------------
template <int NKT, int ASTR, bool RELU_A, bool BIAS_RELU>
__global__ __launch_bounds__(256) void mfma_gemm(
    const unsigned short* __restrict__ Ab,
    const unsigned short* __restrict__ Wt,  // [320][NKT*32]
    const float* __restrict__ bias,
    bf16* __restrict__ out,
    int M)
{
    constexpr int KTOT = NKT * 32;

    __shared__ char As[2][64 * 64];   // 2 x 4KB double-buffered A
    __shared__ char Cs[16 * 640];     // 10KB epilogue staging

    const int t    = threadIdx.x;
    const int m0   = blockIdx.x * 64;
    const int wc   = t >> 6;          // wave = col strip
    const int lane = t & 63;
    const int l16  = lane & 15;
    const int quad = lane >> 4;

    // A-staging mapping: thread t stages 16B of row t>>2, chunk t&3
    const int am = t >> 2;
    const int c  = t & 3;
    const int gm = min(m0 + am, M - 1);
    const unsigned short* const agp = Ab + (long)gm * ASTR + c * 8;
    char* const lds0 = As[0] + t * 16;
    char* const lds1 = As[1] + t * 16;

    auto load_b = [&](int kt, short8* bfr) {
        const int kbase = kt * 32 + quad * 8;
#pragma unroll
        for (int nt = 0; nt < 5; ++nt) {
            const int nn = wc * 80 + nt * 16 + l16;
            bfr[nt] = *(const short8*)(Wt + (long)nn * KTOT + kbase);
        }
    };

    f32x4 acc[4][5];
#pragma unroll
    for (int i = 0; i < 4; ++i)
#pragma unroll
        for (int j = 0; j < 5; ++j) acc[i][j] = (f32x4){0.f, 0.f, 0.f, 0.f};

    // prologue: stage A(0) async, wait once
    gload16(agp, lds0);
    __syncthreads();

    for (int kt = 0; kt < NKT; ++kt) {
        short8 bfr[5];
        load_b(kt, bfr);                          // current-step B (L2)
        if (kt + 1 < NKT)
            gload16(agp + (kt + 1) * 32, ((kt + 1) & 1) ? lds1 : lds0);  // async next A
        short8 afr[4];
#pragma unroll
        for (int mt = 0; mt < 4; ++mt) {
            short8 v = *(const short8*)(As[kt & 1] + (mt * 16 + l16) * 64 + quad * 16);
            if (RELU_A) {                         // relu on bf16: clear negatives
                unsigned short* rp = (unsigned short*)&v;
#pragma unroll
                for (int j = 0; j < 8; ++j)
                    rp[j] = (rp[j] & 0x8000u) ? 0 : rp[j];
            }
            afr[mt] = v;
        }
#pragma unroll
        for (int nt = 0; nt < 5; ++nt)
#pragma unroll
            for (int mt = 0; mt < 4; ++mt)
                acc[mt][nt] = __builtin_amdgcn_mfma_f32_16x16x32_bf16(
                    afr[mt], bfr[nt], acc[mt][nt], 0, 0, 0);
        __syncthreads();   // drains the async stage (issued one MFMA block ago)
    }

    // epilogue: per 16-row strip, LDS transpose -> coalesced 16B stores
    for (int mt = 0; mt < 4; ++mt) {
        __syncthreads();
#pragma unroll
        for (int nt = 0; nt < 5; ++nt) {
            const int col = wc * 80 + nt * 16 + l16;
            float bv = 0.f;
            if (BIAS_RELU) bv = (col < H_DIM) ? bias[col] : 0.f;
#pragma unroll
            for (int r = 0; r < 4; ++r) {
                float v = acc[mt][nt][r] + bv;
                if (BIAS_RELU) v = fmaxf(v, 0.f);
                ((unsigned short*)Cs)[(quad * 4 + r) * HP + col] = f2b_raw(v);
            }
        }
        __syncthreads();
        const int gr0 = m0 + mt * 16;
#pragma unroll
        for (int i = 0; i < 3; ++i) {       // 640 16B-chunks, 256 threads
            const int idx = i * 256 + t;
            if (idx < 640) {
                const int row = idx / 40;   // 40 chunks per 640B row
                if (gr0 + row < M)
                    *(uint4*)((char*)out + (long)(gr0 + row) * 640 + (idx - row * 40) * 16)
                        = *(const uint4*)(Cs + idx * 16);
            }
        }
    }
}

// amsg[a][0:320] = sum_{j<6} msg[a2b[a][j]][0:320]; thread = (atom, 8-col chunk)
// out rows at stride ostride (ushorts)
__global__ __launch_bounds__(256) void gather_sum_kernel(
    const bf16* __restrict__ msg, const int* __restrict__ a2b,
    unsigned short* __restrict__ amsg, int ostride, int n_atoms)
{
    const int idx = blockIdx.x * 256 + threadIdx.x;
    if (idx >= n_atoms * (HP / 8)) return;
    const int a = idx / (HP / 8);
    const int cc = idx - a * (HP / 8);
    float s[8] = {0.f, 0.f, 0.f, 0.f, 0.f, 0.f, 0.f, 0.f};
    const int base = a * MAXNB;
#pragma unroll
    for (int j = 0; j < MAXNB; ++j) {
        const long b = a2b[base + j];
        const uint4 u = *(const uint4*)((const char*)msg + (b * HP + cc * 8) * 2);
        const unsigned short* up = (const unsigned short*)&u;
#pragma unroll
        for (int e = 0; e < 8; ++e) s[e] += b2f_raw(up[e]);
    }
    uint4 r;
    unsigned short* rp = (unsigned short*)&r;
#pragma unroll
    for (int e = 0; e < 8; ++e) rp[e] = f2b_raw(s[e]);
    *(uint4*)(amsg + (long)a * ostride + cc * 8) = r;
}

// msg'[b] = relu(inp[b] + Gh[b2a[b]] - Hm[b2revb[b]]); thread = (bond, 8-col chunk)
__global__ __launch_bounds__(256) void combine_kernel(
    const bf16* __restrict__ inp, const bf16* __restrict__ Gh,
    const bf16* __restrict__ Hm, const int* __restrict__ b2a,
    const int* __restrict__ b2revb, bf16* __restrict__ outm, int n_bonds)
{
    const int idx = blockIdx.x * 256 + threadIdx.x;
    if (idx >= n_bonds * (HP / 8)) return;
    const int b = idx / (HP / 8);
    const int cc = idx - b * (HP / 8);
    const long co = (long)cc * 16;
    const long ra = b2a[b];
    const long rb = b2revb[b];
    const uint4 vi = *(const uint4*)((const char*)inp + (long)b * 640 + co);
    const uint4 vg = *(const uint4*)((const char*)Gh + ra * 640 + co);
    const uint4 vh = *(const uint4*)((const char*)Hm + rb * 640 + co);
    const unsigned short* ip = (const unsigned short*)&vi;
    const unsigned short* gp = (const unsigned short*)&vg;
    const unsigned short* hp = (const unsigned short*)&vh;
    uint4 r;
    unsigned short* rp = (unsigned short*)&r;
#pragma unroll
    for (int e = 0; e < 8; ++e) {
        const float v = b2f_raw(ip[e]) + b2f_raw(gp[e]) - b2f_raw(hp[e]);
        rp[e] = f2b_raw(fmaxf(v, 0.f));
    }
    *(uint4*)((char*)outm + (long)b * 640 + co) = r;
}

// Per-molecule mean; atom_mol sorted ascending -> binary search range, no atomics.
__global__ __launch_bounds__(256) void seg_mean_kernel(
    const bf16* __restrict__ hidden, const int* __restrict__ atom_mol,
    float* __restrict__ out, int n_atoms)
{
    const int m = blockIdx.x;
    __shared__ int s_lo, s_hi;
    if (threadIdx.x == 0) {
        int lo = 0, hi = n_atoms;
        while (lo < hi) { int mid = (lo + hi) >> 1; if (atom_mol[mid] < m) lo = mid + 1; else hi = mid; }
        s_lo = lo;
        int lo2 = lo; hi = n_atoms;
        while (lo2 < hi) { int mid = (lo2 + hi) >> 1; if (atom_mol[mid] < m + 1) lo2 = mid + 1; else hi = mid; }
        s_hi = lo2;
    }
    __syncthreads();
    const int lo = s_lo, hi = s_hi;
    const float inv = 1.0f / (float)max(hi - lo, 1);
    for (int cpass = 0; cpass < 2; ++cpass) {
        const int c = cpass * 256 + threadIdx.x;
        if (c >= H_DIM) break;
        float s = 0.f;
        for (int a = lo; a < hi; ++a)
            s += b2f_raw(((const unsigned short*)hidden)[(long)a * HP + c]);
        out[(long)m * H_DIM + c] = s * inv;
    }
}

extern "C" void kernel_launch(void* const* d_in, const int* in_sizes, int n_in,
                              void* d_out, int out_size, void* d_ws, size_t ws_size,
                              hipStream_t stream)
{
    const float* f_atoms = (const float*)d_in[0];
    const float* f_bonds = (const float*)d_in[1];
    const float* W_i     = (const float*)d_in[2];
    const float* W_h     = (const float*)d_in[3];
    const float* W_o     = (const float*)d_in[4];
    const float* b_o     = (const float*)d_in[5];
    const int*  a2b      = (const int*)d_in[6];
    const int*  b2a      = (const int*)d_in[7];
    const int*  b2revb   = (const int*)d_in[8];
    const int*  atom_mol = (const int*)d_in[9];

    const int n_atoms = in_sizes[0] / AF_DIM;   // 100000
    const int n_bonds = in_sizes[1] / BF_DIM;   // 200000
    const int n_mols  = out_size / H_DIM;       // 4000

    char* ws = (char*)d_ws;
    size_t off = 0;
    auto alloc = [&](size_t bytes) {
        size_t o = off; off += (bytes + 255) & ~(size_t)255; return o;
    };
    bf16* inpB = (bf16*)(ws + alloc((size_t)n_bonds * HP * 2));   // 128 MB (raw inp)
    bf16* msgX = (bf16*)(ws + alloc((size_t)n_bonds * HP * 2));   // 128 MB (msg1/msg2)
    bf16* HmB  = (bf16*)(ws + alloc((size_t)n_bonds * HP * 2));   // 128 MB (Hm per layer)
    bf16* amsg = (bf16*)(ws + alloc((size_t)n_atoms * HP * 2));   //  64 MB (Gh)
    unsigned short* Wt1 = (unsigned short*)(ws + alloc(320 * 160 * 2));
    unsigned short* WtH = (unsigned short*)(ws + alloc(320 * 320 * 2));
    unsigned short* Wt3 = (unsigned short*)(ws + alloc(320 * 480 * 2));
    // Aliases (lifetime-disjoint):
    unsigned short* fb16    = (unsigned short*)HmB;   // f_bonds bf16 [2e5][160]; dead after M1
    unsigned short* atomcat = (unsigned short*)inpB;  // [1e5][480]: cols 0-319 gsum, 320+ f_atoms;
                                                      // prepped after combine-2 (inp dead)
    bf16* hidden = HmB;                               // HmB dead after combine-2

    const dim3 blk(256);

    // weight prep (Wt3: amsg part = W_o rows 133.., atom part = W_o rows 0..132)
    prep_wt<<<(320 * 160 + 255) / 256, blk, 0, stream>>>(W_i, BF_DIM, nullptr, 0, Wt1, 5);
    prep_wt<<<(320 * 320 + 255) / 256, blk, 0, stream>>>(W_h, H_DIM, nullptr, 0, WtH, 10);
    prep_wt<<<(320 * 480 + 255) / 256, blk, 0, stream>>>(W_o + (size_t)AF_DIM * H_DIM, H_DIM,
                                                         W_o, AF_DIM, Wt3, 15);

    const int gB = (n_bonds + 63) / 64;   // 3125
    const int gA = (n_atoms + 63) / 64;   // 1563
    const int gG = (n_atoms * (HP / 8) + 255) / 256;
    const int gC = (n_bonds * (HP / 8) + 255) / 256;

    // f_bonds -> bf16 [n_bonds][160] (into HmB area)
    prep_cvt<<<(n_bonds * 20 + 255) / 256, blk, 0, stream>>>(f_bonds, BF_DIM, fb16, 160, n_bonds);

    // inp = f_bonds16 @ W_i (raw; msg0 = relu(inp) folded into layer-1 A-read)
    mfma_gemm<5, 160, false, false><<<gB, blk, 0, stream>>>(fb16, Wt1, nullptr, inpB, n_bonds);

    // layer 1: Hm = relu(inp)@W_h; Gh = gsum(Hm); msg1 = relu(inp + Gh[b2a] - Hm[b2revb])
    mfma_gemm<10, 320, true, false><<<gB, blk, 0, stream>>>(
        (const unsigned short*)inpB, WtH, nullptr, HmB, n_bonds);
    gather_sum_kernel<<<gG, blk, 0, stream>>>(HmB, a2b, (unsigned short*)amsg, HP, n_atoms);
    combine_kernel<<<gC, blk, 0, stream>>>(inpB, amsg, HmB, b2a, b2revb, msgX, n_bonds);

    // layer 2
    mfma_gemm<10, 320, false, false><<<gB, blk, 0, stream>>>(
        (const unsigned short*)msgX, WtH, nullptr, HmB, n_bonds);
    gather_sum_kernel<<<gG, blk, 0, stream>>>(HmB, a2b, (unsigned short*)amsg, HP, n_atoms);
    combine_kernel<<<gC, blk, 0, stream>>>(inpB, amsg, HmB, b2a, b2revb, msgX, n_bonds);

    // readout: atomcat cols 320+ = f_atoms bf16 (inp dead now); cols 0-319 = gsum(msg2)
    prep_cvt<<<(n_atoms * 20 + 255) / 256, blk, 0, stream>>>(f_atoms, AF_DIM, atomcat + 320, 480, n_atoms);
    gather_sum_kernel<<<gG, blk, 0, stream>>>(msgX, a2b, atomcat, 480, n_atoms);
    mfma_gemm<15, 480, false, true><<<gA, blk, 0, stream>>>(atomcat, Wt3, b_o, hidden, n_atoms);

    // per-molecule mean
    seg_mean_kernel<<<n_mols, blk, 0, stream>>>(hidden, atom_mol, (float*)d_out, n_atoms);
}